// Round 9
// baseline (251.670 us; speedup 1.0000x reference)
//
#include <hip/hip_runtime.h>

#define NPI    33600     // anchors per image: 160^2 + 80^2 + 40^2
#define KTOP   500
#define CAP    1024
#define KEY001 0xBC23D70Au   // monotonic key of 0.01f
#define NGRP   1024
#define NIMG   8
#define NBLK   132       // k_score blocks per image (100 + 25 + 7)
#define BCAPB  528       // candB storage (>= any non-degenerate boundary bin)

__device__ __forceinline__ float sigmoidf_(float x) {
  return 1.0f / (1.0f + expf(-x));
}
// monotonic float -> u32 key (order-preserving for all non-NaN floats)
__device__ __forceinline__ unsigned fkey(float f) {
  unsigned u = __float_as_uint(f);
  return (u & 0x80000000u) ? ~u : (u | 0x80000000u);
}
__device__ __forceinline__ float rdlanef(float v, int l) {
  return __uint_as_float((unsigned)__builtin_amdgcn_readlane((int)__float_as_uint(v), l));
}

// ---------------- Kernel 1: streaming score+argmax pass ----------------
// 64-thread blocks, 256 anchors each (132/img, 1056 total = 4.1/CU, balanced).
// Exact per-class sigmoid argmax (first occurrence). Outputs keys + cc/lab/obj
// planes + per-block hist row (plain stores, no memset needed).
__global__ __launch_bounds__(64, 1) void k_score(
    const float* __restrict__ p8, const float* __restrict__ p16,
    const float* __restrict__ p32,
    unsigned* __restrict__ keys, float* __restrict__ ccv,
    float* __restrict__ labv, float* __restrict__ objv,
    unsigned* __restrict__ histp)
{
  const int b  = blockIdx.y;
  const int xb = blockIdx.x;
  const float* lvl; int HW, j0, abase;
  if (xb < 100)      { lvl = p8;  HW = 25600; j0 = xb * 256;         abase = 0; }
  else if (xb < 125) { lvl = p16; HW = 6400;  j0 = (xb - 100) * 256; abase = 25600; }
  else               { lvl = p32; HW = 1600;  j0 = (xb - 125) * 256; abase = 32000; }
  __shared__ unsigned lh[NGRP];
  for (int i = threadIdx.x; i < NGRP; i += 64) lh[i] = 0;
  __syncthreads();

  const int e = j0 + 4 * (int)threadIdx.x;
  if (e < HW) {
    const float* base = lvl + (size_t)b * 85 * HW + e;
    float4 o4 = *(const float4*)(base + (size_t)4 * HW);
    // exact per-class sigmoid argmax, first occurrence (strict >)
    float cc[4] = {-1.0f, -1.0f, -1.0f, -1.0f};
    int   lab[4] = {0, 0, 0, 0};
    for (int c0 = 0; c0 < 80; c0 += 16) {
      float4 r[16];
      #pragma unroll
      for (int u = 0; u < 16; ++u)
        r[u] = *(const float4*)(base + (size_t)(5 + c0 + u) * HW);
      #pragma unroll
      for (int u = 0; u < 16; ++u) {
        float s;
        s = sigmoidf_(r[u].x); if (s > cc[0]) { cc[0] = s; lab[0] = c0 + u; }
        s = sigmoidf_(r[u].y); if (s > cc[1]) { cc[1] = s; lab[1] = c0 + u; }
        s = sigmoidf_(r[u].z); if (s > cc[2]) { cc[2] = s; lab[2] = c0 + u; }
        s = sigmoidf_(r[u].w); if (s > cc[3]) { cc[3] = s; lab[3] = c0 + u; }
      }
    }
    float ov[4] = {o4.x, o4.y, o4.z, o4.w};
    unsigned k4[4];
    float ob[4], lf[4];
    #pragma unroll
    for (int q = 0; q < 4; ++q) {
      ob[q] = sigmoidf_(ov[q]);
      float tot = ob[q] * cc[q];                 // obj * class_conf (ref)
      k4[q] = fkey(tot >= 0.01f ? tot : -1.0f);
      lf[q] = (float)lab[q];
    }
    const size_t pa = (size_t)b * NPI + abase + e;
    *(uint4*)(keys + pa)  = make_uint4(k4[0], k4[1], k4[2], k4[3]);
    *(float4*)(ccv + pa)  = make_float4(cc[0], cc[1], cc[2], cc[3]);
    *(float4*)(labv + pa) = make_float4(lf[0], lf[1], lf[2], lf[3]);
    *(float4*)(objv + pa) = make_float4(ob[0], ob[1], ob[2], ob[3]);
    #pragma unroll
    for (int q = 0; q < 4; ++q) atomicAdd(&lh[k4[q] >> 22], 1u);
  }
  __syncthreads();
  unsigned* gb = histp + ((size_t)b * NBLK + xb) * NGRP;
  for (int i = threadIdx.x; i < NGRP; i += 64) gb[i] = lh[i];   // plain stores
}

// ---------------- Kernel 2: fused select + sort + gather + IoU + NMS ----------
__global__ __launch_bounds__(512, 1) void k_post(
    const float* __restrict__ p8, const float* __restrict__ p16,
    const float* __restrict__ p32,
    const unsigned* __restrict__ histp, const unsigned* __restrict__ keys,
    const float* __restrict__ ccv, const float* __restrict__ labv,
    const float* __restrict__ objv, float* __restrict__ out)
{
  const int b    = blockIdx.x;
  const int tid  = threadIdx.x;
  const int lane = tid & 63;
  const int wave = tid >> 6;

  __shared__ unsigned lh[NGRP];                         // 4 KB coarse hist
  __shared__ unsigned sh_sub[4096];                     // 16 KB refine hist
  __shared__ unsigned sh_c64[64];
  __shared__ unsigned sh_G, sh_chi10, sh_T;
  __shared__ int sh_ctrA, sh_ctrB;
  __shared__ __align__(16) unsigned long long sh_cand[CAP];     // 8 KB
  __shared__ __align__(16) unsigned long long sh_candB[BCAPB];  // 4.2 KB
  __shared__ unsigned sh_sel[KTOP];                     // 2 KB anchor ids
  __shared__ float sh_det[KTOP][7];                     // 14 KB
  __shared__ float sx1[512], sy1[512], sx2[512], sy2[512], sa[512]; // 10 KB
  __shared__ unsigned sh_mask[KTOP * 17];               // 34 KB (stride 17!)
  __shared__ unsigned sh_inval[16];
  __shared__ unsigned sh_keep[16];
  __shared__ unsigned sh_wcB[8];
  __shared__ float sh_red[8];
  __shared__ float sh_maxc;

  // ---- A1: sum per-block hist rows -> lh (coalesced)
  {
    unsigned s0 = 0, s1 = 0;
    for (int r = 0; r < NBLK; ++r) {
      const unsigned* row = histp + ((size_t)b * NBLK + r) * NGRP;
      s0 += row[tid]; s1 += row[tid + 512];
    }
    lh[tid] = s0; lh[tid + 512] = s1;
  }
  for (int i = tid; i < 4096; i += 512) sh_sub[i] = 0;
  if (tid == 0) { sh_ctrA = 0; sh_ctrB = 0; }
  __syncthreads();
  if (tid < 64) {
    unsigned s = 0;
    #pragma unroll
    for (int k = 0; k < 16; ++k) s += lh[tid * 16 + ((k + tid) & 15)]; // swizzled
    sh_c64[tid] = s;
  }
  __syncthreads();
  // ---- wave-parallel two-level scan -> G, chi10
  if (wave == 0) {
    unsigned v = sh_c64[lane];
    unsigned t = v;
    #pragma unroll
    for (int off = 1; off < 64; off <<= 1) {
      unsigned o = (unsigned)__shfl_down((int)t, off);
      if (lane + off < 64) t += o;
    }
    unsigned long long m = __ballot(t >= KTOP);
    int C = 63 - __builtin_clzll(m);           // highest lane with suffix >= KTOP
    unsigned cumAfter = (unsigned)__shfl((int)t, C) - (unsigned)__shfl((int)v, C);
    unsigned v2 = (lane < 16) ? lh[C * 16 + lane] : 0u;
    unsigned t2 = v2;
    #pragma unroll
    for (int off = 1; off < 16; off <<= 1) {
      unsigned o = (unsigned)__shfl_down((int)t2, off);
      if (lane + off < 16) t2 += o;
    }
    t2 += cumAfter;
    unsigned long long m2 = __ballot((lane < 16) && (t2 >= KTOP));
    int Gl = 63 - __builtin_clzll(m2);
    if (lane == 0) {
      sh_G = (unsigned)(C * 16 + Gl);
      sh_chi10 = (unsigned)__shfl((int)t2, Gl) - (unsigned)__shfl((int)v2, Gl);
    }
  }
  __syncthreads();
  const unsigned G = sh_G;
  const unsigned* kb = keys + (size_t)b * NPI;

  // ---- A2: 4096-bin sub-hist of bits [21:10] within group G
  for (int g = tid; g < NPI / 4; g += 512) {
    uint4 kv = ((const uint4*)kb)[g];
    unsigned kk[4] = {kv.x, kv.y, kv.z, kv.w};
    #pragma unroll
    for (int q = 0; q < 4; ++q)
      if ((kk[q] >> 22) == G) atomicAdd(&sh_sub[(kk[q] >> 10) & 4095u], 1u);
  }
  __syncthreads();
  if (tid < 64) {
    unsigned s = 0;
    for (int k = 0; k < 64; ++k) s += sh_sub[tid * 64 + ((k + tid) & 63)]; // swizzled
    sh_c64[tid] = s;
  }
  __syncthreads();
  if (wave == 0) {
    unsigned chi10 = sh_chi10;
    unsigned v = sh_c64[lane];
    unsigned t = v;
    #pragma unroll
    for (int off = 1; off < 64; off <<= 1) {
      unsigned o = (unsigned)__shfl_down((int)t, off);
      if (lane + off < 64) t += o;
    }
    t += chi10;
    unsigned long long m = __ballot(t >= KTOP);
    int C2 = 63 - __builtin_clzll(m);
    unsigned after = (unsigned)__shfl((int)t, C2) - (unsigned)__shfl((int)v, C2);
    unsigned v3 = sh_sub[C2 * 64 + lane];
    unsigned t3 = v3;
    #pragma unroll
    for (int off = 1; off < 64; off <<= 1) {
      unsigned o = (unsigned)__shfl_down((int)t3, off);
      if (lane + off < 64) t3 += o;
    }
    t3 += after;
    unsigned long long m3 = __ballot(t3 >= KTOP);
    int Gl = 63 - __builtin_clzll(m3);
    if (lane == 0) sh_T = (G << 12) | (unsigned)(C2 * 64 + Gl);   // 22-bit threshold
  }
  __syncthreads();
  const unsigned T = sh_T;

  // ---- Single-pass ballot-aggregated compaction (order-free; sort fixes order)
  for (int it = 0; it < 17; ++it) {
    int g = it * 512 + tid;
    bool act = (g < NPI / 4);
    uint4 kv = act ? ((const uint4*)kb)[g] : make_uint4(0, 0, 0, 0);
    unsigned kk[4] = {kv.x, kv.y, kv.z, kv.w};
    bool iA[4], iB[4];
    unsigned long long balA[4], balB[4];
    unsigned tA = 0, tB = 0;
    #pragma unroll
    for (int q = 0; q < 4; ++q) {
      unsigned bin = kk[q] >> 10;
      iA[q] = act && (bin > T);
      iB[q] = act && (bin == T);
      balA[q] = __ballot(iA[q]);
      balB[q] = __ballot(iB[q]);
      tA += (unsigned)__popcll(balA[q]);
      tB += (unsigned)__popcll(balB[q]);
    }
    int bA = 0, bB = 0;
    if (lane == 0) {
      if (tA) bA = atomicAdd(&sh_ctrA, (int)tA);
      if (tB) bB = atomicAdd(&sh_ctrB, (int)tB);
    }
    bA = __shfl(bA, 0); bB = __shfl(bB, 0);
    unsigned long long lt = (1ULL << lane) - 1ULL;
    unsigned offA = 0, offB = 0;
    #pragma unroll
    for (int q = 0; q < 4; ++q) {
      unsigned posA = (unsigned)bA + offA + (unsigned)__popcll(balA[q] & lt);
      unsigned posB = (unsigned)bB + offB + (unsigned)__popcll(balB[q] & lt);
      unsigned long long packed =
          ((unsigned long long)kk[q] << 32) |
          (unsigned long long)(0xFFFFFFFFu - (unsigned)(g * 4 + q));
      if (iA[q]) sh_cand[posA] = packed;
      if (iB[q] && posB < BCAPB) sh_candB[posB] = packed;
      offA += (unsigned)__popcll(balA[q]);
      offB += (unsigned)__popcll(balB[q]);
    }
  }
  __syncthreads();
  const int nA    = sh_ctrA;                  // < KTOP by construction of T
  const int nBtot = sh_ctrB;
  const int Bcap  = CAP - nA;
  const bool fast = (nBtot <= Bcap) && (nBtot <= BCAPB);
  int nBk;
  if (fast) {
    nBk = nBtot;
    for (int i2 = tid; i2 < nBtot; i2 += 512) sh_cand[nA + i2] = sh_candB[i2];
  } else {
    // Fallback (degenerate boundary bin): ordered two-pass for B, lowest idx kept
    nBk = (nBtot < Bcap) ? nBtot : Bcap;
    const int GPW2 = NPI / 4 / 8;             // 1050 groups per wave
    unsigned runB = 0;
    for (int it = 0; it < 17; ++it) {
      int gl = it * 64 + lane;
      bool act = (gl < GPW2);
      int g = wave * GPW2 + gl;
      uint4 kv = act ? ((const uint4*)kb)[g] : make_uint4(0, 0, 0, 0);
      unsigned kk[4] = {kv.x, kv.y, kv.z, kv.w};
      #pragma unroll
      for (int q = 0; q < 4; ++q)
        runB += (unsigned)__popcll(__ballot(act && ((kk[q] >> 10) == T)));
    }
    if (lane == 0) sh_wcB[wave] = runB;
    __syncthreads();
    unsigned pB = 0;
    for (int w2 = 0; w2 < wave; ++w2) pB += sh_wcB[w2];
    for (int it = 0; it < 17; ++it) {
      int gl = it * 64 + lane;
      bool act = (gl < GPW2);
      int g = wave * GPW2 + gl;
      uint4 kv = act ? ((const uint4*)kb)[g] : make_uint4(0, 0, 0, 0);
      unsigned kk[4] = {kv.x, kv.y, kv.z, kv.w};
      unsigned long long lt = (1ULL << lane) - 1ULL;
      #pragma unroll
      for (int q = 0; q < 4; ++q) {
        bool iB = act && ((kk[q] >> 10) == T);
        unsigned long long bal = __ballot(iB);
        unsigned pBl = pB + (unsigned)__popcll(bal & lt);
        if (iB && pBl < (unsigned)Bcap) {
          sh_cand[nA + pBl] =
              ((unsigned long long)kk[q] << 32) |
              (unsigned long long)(0xFFFFFFFFu - (unsigned)(g * 4 + q));
        }
        pB += (unsigned)__popcll(bal);
      }
    }
  }
  const int nTot = nA + nBk;                  // in [KTOP, CAP]
  const int P = (nTot <= 512) ? 512 : 1024;
  __syncthreads();
  for (int s = nTot + tid; s < P; s += 512) sh_cand[s] = 0ULL;
  __syncthreads();

  // ---- Bitonic sort P u64 descending ((score desc, index asc)); 1 exch/thread
  {
    const int half = P >> 1;
    for (unsigned kk2 = 2; kk2 <= (unsigned)P; kk2 <<= 1) {
      for (unsigned jj = kk2 >> 1; jj > 0; jj >>= 1) {
        if (tid < half) {
          unsigned i = (((unsigned)tid & ~(jj - 1)) << 1) | ((unsigned)tid & (jj - 1));
          unsigned p = i | jj;
          unsigned long long x = sh_cand[i], y = sh_cand[p];
          bool desc = ((i & kk2) == 0);
          if ((x < y) == desc) { sh_cand[i] = y; sh_cand[p] = x; }
        }
        __syncthreads();
      }
    }
  }

  // ---- Selected anchors + invalid bitset
  bool validk = false;
  if (tid < KTOP) {
    unsigned long long v = sh_cand[tid];
    unsigned keyk = (unsigned)(v >> 32);
    int a = (int)(0xFFFFFFFFu - (unsigned)(v & 0xFFFFFFFFull));
    if (a < 0) a = 0;                 // zero-padded slot (invalid anyway)
    sh_sel[tid] = (unsigned)a;
    validk = (keyk >= KEY001);
  }
  {
    unsigned long long bv = __ballot((tid < KTOP) && !validk);
    if (lane == 0) {
      sh_inval[wave * 2]     = (unsigned)(bv & 0xFFFFFFFFull);
      sh_inval[wave * 2 + 1] = (unsigned)(bv >> 32);
    }
  }
  __syncthreads();

  // ---- Gather: 16 lanes per selected anchor; only t0..t3 scattered + planes
  {
    const int p   = tid & 15;
    const int grp = tid >> 4;           // 32 groups
    const int g0  = lane & ~15;
    for (int it = 0; it < 16; ++it) {
      int s = it * 32 + grp;
      if (s >= KTOP) continue;
      int a = (int)sh_sel[s];
      const float* lvl; int j, W, HW, S;
      if (a < 25600)      { lvl = p8;  j = a;         W = 160; HW = 25600; S = 8;  }
      else if (a < 32000) { lvl = p16; j = a - 25600; W = 80;  HW = 6400;  S = 16; }
      else                { lvl = p32; j = a - 32000; W = 40;  HW = 1600;  S = 32; }
      const size_t pa = (size_t)b * NPI + (size_t)a;
      float tl = 0.0f;
      if (p < 4)       tl = lvl[(size_t)b * 85 * HW + (size_t)p * HW + j];
      else if (p == 4) tl = objv[pa];
      else if (p == 5) tl = ccv[pa];
      else if (p == 6) tl = labv[pa];
      float t0 = __shfl(tl, g0 + 0);
      float t1 = __shfl(tl, g0 + 1);
      float t2 = __shfl(tl, g0 + 2);
      float t3 = __shfl(tl, g0 + 3);
      float ob = __shfl(tl, g0 + 4);
      float cc = __shfl(tl, g0 + 5);
      float lf = __shfl(tl, g0 + 6);
      if (p == 0) {
        int gy = j / W, gx = j - gy * W;
        float fs = (float)S;
        float cx = (t0 + (float)gx) * fs;
        float cy = (t1 + (float)gy) * fs;
        float w  = expf(t2) * fs;
        float h  = expf(t3) * fs;
        sh_det[s][0] = cx - 0.5f * w; sh_det[s][1] = cy - 0.5f * h;
        sh_det[s][2] = cx + 0.5f * w; sh_det[s][3] = cy + 0.5f * h;
        sh_det[s][4] = ob; sh_det[s][5] = cc; sh_det[s][6] = lf;
      }
    }
  }
  __syncthreads();

  // ---- max_c: max over valid of max(x1,y1,x2,y2); invalid contribute 0 (ref)
  {
    float contrib = 0.0f;
    if (tid < KTOP) {
      bool valid = ((sh_inval[tid >> 5] >> (tid & 31)) & 1u) == 0u;
      float m4 = fmaxf(fmaxf(sh_det[tid][0], sh_det[tid][1]),
                       fmaxf(sh_det[tid][2], sh_det[tid][3]));
      contrib = valid ? m4 : 0.0f;
    }
    #pragma unroll
    for (int off = 32; off > 0; off >>= 1)
      contrib = fmaxf(contrib, __shfl_xor(contrib, off));
    if (lane == 0) sh_red[wave] = contrib;
    __syncthreads();
    if (tid == 0) {
      float m = 0.0f;
      for (int w2 = 0; w2 < 8; ++w2) m = fmaxf(m, sh_red[w2]);
      sh_maxc = m + 1.0f;
    }
  }
  __syncthreads();
  const float maxc = sh_maxc;
  {
    float x1, y1, x2, y2, ar;
    if (tid < KTOP) {
      float offb = sh_det[tid][6] * maxc;   // label * max_c
      x1 = sh_det[tid][0] + offb; y1 = sh_det[tid][1] + offb;
      x2 = sh_det[tid][2] + offb; y2 = sh_det[tid][3] + offb;
      ar = fmaxf(x2 - x1, 0.0f) * fmaxf(y2 - y1, 0.0f);   // area of OFFSET box (ref)
    } else { x1 = y1 = x2 = y2 = ar = 0.0f; }
    sx1[tid] = x1; sy1[tid] = y1; sx2[tid] = x2; sy2[tid] = y2; sa[tid] = ar;
  }
  __syncthreads();

  // ---- IoU bitmask: register-cached j-boxes + readlane (VALU-only broadcast).
  // Wave w owns column block cb (triangle-balanced pairing across SIMDs).
  {
    const int cb = (wave < 4) ? (7 - wave) : (wave - 4);
    const int jb = cb * 64;
    float jx1 = sx1[jb + lane], jy1 = sy1[jb + lane];
    float jx2 = sx2[jb + lane], jy2 = sy2[jb + lane];
    float ja  = sa[jb + lane];
    for (int it = 0; it <= cb; ++it) {
      int i = it * 64 + lane;
      float ix1 = sx1[i], iy1 = sy1[i], ix2 = sx2[i], iy2 = sy2[i];
      float a1 = sa[i];
      unsigned w0 = 0u, w1 = 0u;
      #pragma unroll
      for (int jj = 0; jj < 64; ++jj) {
        int j = jb + jj;
        float bx1 = rdlanef(jx1, jj);
        float by1 = rdlanef(jy1, jj);
        float bx2 = rdlanef(jx2, jj);
        float by2 = rdlanef(jy2, jj);
        float ba  = rdlanef(ja,  jj);
        if (j < KTOP && j > i) {
          float iw = fminf(ix2, bx2) - fmaxf(ix1, bx1);
          float ih = fminf(iy2, by2) - fmaxf(iy1, by1);
          float inter = fmaxf(iw, 0.0f) * fmaxf(ih, 0.0f);
          // iou > 0.65  <=>  inter > 0.65*(a1+a2-inter+1e-9)
          if (inter > 0.65f * (a1 + ba - inter + 1e-9f)) {
            if (jj < 32) w0 |= (1u << jj); else w1 |= (1u << (jj - 32));
          }
        }
      }
      if (i < KTOP) {
        sh_mask[i * 17 + 2 * cb]     = w0;   // stride 17 -> conflict-free stores
        sh_mask[i * 17 + 2 * cb + 1] = w1;
      }
    }
  }
  __syncthreads();

  // ---- Greedy sequential scan (wave 0); lane l<16 owns suppressed word l
  if (tid < 64) {
    unsigned sup   = (lane < 16) ? sh_inval[lane] : 0u;
    unsigned keepw = 0u;
    unsigned cur = (unsigned)__builtin_amdgcn_readlane((int)sup, 0);
    unsigned mA = (lane < 16) ? sh_mask[0 * 17 + lane] : 0u;
    unsigned mB = (lane < 16) ? sh_mask[1 * 17 + lane] : 0u;
    for (int i = 0; i < KTOP; i += 2) {
      bool ok = ((cur >> (i & 31)) & 1u) == 0u;
      if (ok) {
        sup |= mA;
        if (lane == (i >> 5)) keepw |= (1u << (i & 31));
      }
      cur = (unsigned)__builtin_amdgcn_readlane((int)sup, (i + 1) >> 5);
      mA = (lane < 16 && (i + 2) < KTOP) ? sh_mask[(i + 2) * 17 + lane] : 0u;
      bool ok2 = ((cur >> ((i + 1) & 31)) & 1u) == 0u;
      if (ok2) {
        sup |= mB;
        if (lane == ((i + 1) >> 5)) keepw |= (1u << ((i + 1) & 31));
      }
      cur = (unsigned)__builtin_amdgcn_readlane((int)sup, (i + 2) >> 5);
      mB = (lane < 16 && (i + 3) < KTOP) ? sh_mask[(i + 3) * 17 + lane] : 0u;
    }
    if (lane < 16) sh_keep[lane] = keepw;
  }
  __syncthreads();

  // ---- Write det * keep
  for (int x = tid; x < KTOP * 7; x += 512) {
    int k = x / 7, c = x - k * 7;
    float keepf = ((sh_keep[k >> 5] >> (k & 31)) & 1u) ? 1.0f : 0.0f;
    out[(size_t)b * (KTOP * 7) + x] = sh_det[k][c] * keepf;
  }
}

extern "C" void kernel_launch(void* const* d_in, const int* in_sizes, int n_in,
                              void* d_out, int out_size, void* d_ws, size_t ws_size,
                              hipStream_t stream) {
  const float* p8  = (const float*)d_in[0];
  const float* p16 = (const float*)d_in[1];
  const float* p32 = (const float*)d_in[2];
  float* out = (float*)d_out;
  // workspace layout (~8.6 MB — L3-resident)
  unsigned* histp = (unsigned*)d_ws;                        // [8][132][1024]
  unsigned* keys  = histp + (size_t)NIMG * NBLK * NGRP;     // [8][NPI]
  float*    ccv   = (float*)(keys + (size_t)NIMG * NPI);    // [8][NPI]
  float*    labv  = ccv + (size_t)NIMG * NPI;               // [8][NPI]
  float*    objv  = labv + (size_t)NIMG * NPI;              // [8][NPI]

  k_score<<<dim3(NBLK, NIMG), 64, 0, stream>>>(p8, p16, p32, keys, ccv, labv, objv, histp);
  k_post <<<dim3(NIMG), 512, 0, stream>>>(p8, p16, p32, histp, keys, ccv, labv, objv, out);
}